// Round 1
// baseline (430.678 us; speedup 1.0000x reference)
//
#include <hip/hip_runtime.h>
#include <hip/hip_bf16.h>
#include <math.h>

#define NSTREAM 4
#define DIM     1024
#define BUSW    4096
#define NTOK    8192      // B*L = 4*2048
#define NPAD    288       // 256 (res) + 4 (pre) + 4 (post) + pad to 16*18
#define KSPLIT  4
#define KCH     1024      // BUSW / KSPLIT
#define BM      64
#define BK      32
#define OUT0    ((size_t)16 * 2048 * 1024)   // offset of branch_input in d_out

typedef short bf16x8 __attribute__((ext_vector_type(8)));
typedef float f32x4  __attribute__((ext_vector_type(4)));

__device__ __forceinline__ unsigned short f2bf(float f) {
    union { float f; unsigned int u; } x; x.f = f;
    unsigned int r = x.u + 0x7fffu + ((x.u >> 16) & 1u);
    return (unsigned short)(r >> 16);
}
__device__ __forceinline__ unsigned int pack2(float a, float b) {
    return (unsigned int)f2bf(a) | ((unsigned int)f2bf(b) << 16);
}

// ---------------------------------------------------------------------------
// Kernel 1: pack W''[n][k] = (gamma[k]+1) * [phi_res|phi_pre|phi_post|0][k][n]
// stored N-major, K-fast (bf16) so B-fragments are contiguous 16B reads.
// ---------------------------------------------------------------------------
__global__ void prep_w_kernel(const float* __restrict__ gamma,
                              const float* __restrict__ phi_res,
                              const float* __restrict__ phi_pre,
                              const float* __restrict__ phi_post,
                              unsigned short* __restrict__ W) {
    int idx = blockIdx.x * 256 + threadIdx.x;    // idx = n*4096 + k
    int n = idx >> 12;
    int k = idx & 4095;
    float v = 0.0f;
    if (n < 256)      v = phi_res[k * 256 + n];
    else if (n < 260) v = phi_pre[k * 4 + (n - 256)];
    else if (n < 264) v = phi_post[k * 4 + (n - 260)];
    v *= (gamma[k] + 1.0f);
    W[idx] = f2bf(v);
}

// ---------------------------------------------------------------------------
// Kernel 2: raw_part[kc][token][n] = sum_{k in kc-chunk} bus[token][k]*W''[n][k]
// MFMA 16x16x32 bf16. Block: 256 thr (4 waves), BM=64 tokens x NPAD=288 cols,
// BK=32, split-K over blockIdx.y. Wave w: rows (w>>1)*32, cols (w&1)*144.
// ---------------------------------------------------------------------------
__launch_bounds__(256, 2)
__global__ void gemm_raw_kernel(const float* __restrict__ residuals,
                                const unsigned short* __restrict__ W,
                                float* __restrict__ raw_part) {
    __shared__ unsigned short Alds[BM * BK];      // [row][k], k-fast
    __shared__ unsigned short Blds[NPAD * BK];    // [n][k],   k-fast

    const int tid = threadIdx.x;
    const int wid = tid >> 6, lane = tid & 63;
    const int tb = blockIdx.x, kc = blockIdx.y;
    const int row0 = tb * BM;

    f32x4 acc[2][9];
#pragma unroll
    for (int i = 0; i < 2; i++)
#pragma unroll
        for (int j = 0; j < 9; j++) acc[i][j] = (f32x4){0.f, 0.f, 0.f, 0.f};

    // A staging: thread -> (row = tid/4, 8 consecutive k at (tid%4)*8)
    const int arow = tid >> 2;
    const int akq  = (tid & 3) * 8;
    const int tok  = row0 + arow;
    const int bidx = tok >> 11, lidx = tok & 2047;
    // bus k = kc*1024 + (kt*32 + akq); stream = kc (since chunk < 1024)
    const float* abase = residuals +
        (((size_t)(bidx * 4 + kc) * 2048 + lidx) * 1024 + akq);
    const unsigned short* wbase = W + (size_t)kc * KCH;

    const int fr = lane & 15, hf = lane >> 4;
    const int wr = (wid >> 1) * 32;
    const int wc = (wid & 1) * 144;

    for (int kt = 0; kt < KCH / BK; kt++) {
        // stage A (fp32 -> bf16)
        const float* ap = abase + kt * BK;
        float4 f0 = *(const float4*)(ap);
        float4 f1 = *(const float4*)(ap + 4);
        uint4 ua;
        ua.x = pack2(f0.x, f0.y); ua.y = pack2(f0.z, f0.w);
        ua.z = pack2(f1.x, f1.y); ua.w = pack2(f1.z, f1.w);
        *(uint4*)&Alds[arow * BK + akq] = ua;
        // stage B: 288 rows x 32 k = 1152 16B chunks
#pragma unroll
        for (int i = 0; i < 5; i++) {
            int idx = i * 256 + tid;
            if (idx < (NPAD * BK) / 8) {
                int rn = idx >> 2, ko = (idx & 3) * 8;
                uint4 w = *(const uint4*)(wbase + (size_t)rn * BUSW + kt * BK + ko);
                *(uint4*)&Blds[rn * BK + ko] = w;
            }
        }
        __syncthreads();

        bf16x8 afrag[2], bfrag[9];
#pragma unroll
        for (int mt = 0; mt < 2; mt++)
            afrag[mt] = *(const bf16x8*)&Alds[(wr + mt * 16 + fr) * BK + hf * 8];
#pragma unroll
        for (int nt = 0; nt < 9; nt++)
            bfrag[nt] = *(const bf16x8*)&Blds[(wc + nt * 16 + fr) * BK + hf * 8];
#pragma unroll
        for (int mt = 0; mt < 2; mt++)
#pragma unroll
            for (int nt = 0; nt < 9; nt++)
                acc[mt][nt] = __builtin_amdgcn_mfma_f32_16x16x32_bf16(
                    afrag[mt], bfrag[nt], acc[mt][nt], 0, 0, 0);
        __syncthreads();
    }

    // epilogue: C/D mapping col=lane&15, row=(lane>>4)*4+reg
#pragma unroll
    for (int mt = 0; mt < 2; mt++)
#pragma unroll
        for (int nt = 0; nt < 9; nt++)
#pragma unroll
            for (int r = 0; r < 4; r++) {
                int token = row0 + wr + mt * 16 + hf * 4 + r;
                int col   = wc + nt * 16 + fr;
                raw_part[((size_t)kc * NTOK + token) * NPAD + col] = acc[mt][nt][r];
            }
}

// ---------------------------------------------------------------------------
// Kernel 3: per-token fused tail. 1 block (256 thr) per token.
// ---------------------------------------------------------------------------
__global__ void fused_tail_kernel(const float* __restrict__ residuals,
                                  const float* __restrict__ branch_output,
                                  const float* __restrict__ H_res_logits,
                                  const float* __restrict__ alpha_res_p,
                                  const float* __restrict__ H_pre_logits,
                                  const float* __restrict__ alpha_pre_p,
                                  const float* __restrict__ H_post_logits,
                                  const float* __restrict__ alpha_post_p,
                                  const float* __restrict__ raw_part,
                                  float* __restrict__ out) {
    const int t = blockIdx.x;
    const int b = t >> 11, l = t & 2047;
    const int tid = threadIdx.x;
    const int wid = tid >> 6, lane = tid & 63;

    __shared__ float busf[4096];
    __shared__ float Zl[256];
    __shared__ float uu[16], vv[16];
    __shared__ float extra[8];
    __shared__ float hpre[4], hpost[4];
    __shared__ float redbuf[4];
    __shared__ float scale_sh;

    // load bus (4 streams x 1024) + sum of squares
    const float* rbase = residuals + ((size_t)b * 4 * 2048 + l) * 1024;
    float sumsq = 0.f;
#pragma unroll
    for (int s = 0; s < 4; s++) {
        float4 v = *(const float4*)(rbase + (size_t)s * 2048 * 1024 + tid * 4);
        *(float4*)&busf[s * 1024 + tid * 4] = v;
        sumsq += v.x * v.x + v.y * v.y + v.z * v.z + v.w * v.w;
    }
#pragma unroll
    for (int off = 32; off > 0; off >>= 1) sumsq += __shfl_down(sumsq, off, 64);
    if (lane == 0) redbuf[wid] = sumsq;
    __syncthreads();
    if (tid == 0) {
        float ss = redbuf[0] + redbuf[1] + redbuf[2] + redbuf[3];
        scale_sh = 64.0f / fmaxf(sqrtf(ss), 1e-12f);   // sqrt(4096)/||bus||
    }
    __syncthreads();
    const float scale = scale_sh;

    // raw row: sum split-K partials; Z = (alpha*scale*raw + logits)/tau
    const float a_res = alpha_res_p[0];
    float rsum = 0.f;
#pragma unroll
    for (int kc = 0; kc < 4; kc++)
        rsum += raw_part[((size_t)kc * NTOK + t) * NPAD + tid];
    Zl[tid] = (a_res * scale * rsum + H_res_logits[tid]) * (1.0f / 0.05f);
    if (tid < 8) {
        float es = 0.f;
#pragma unroll
        for (int kc = 0; kc < 4; kc++)
            es += raw_part[((size_t)kc * NTOK + t) * NPAD + 256 + tid];
        extra[tid] = es;
    }
    if (tid < 16) vv[tid] = 0.f;
    __syncthreads();

    // H_pre / H_post softmax over 4 streams (thread 0, trivial)
    if (tid == 0) {
        float apre = alpha_pre_p[0], apost = alpha_post_p[0];
        float pv[4], qv[4], pm = -3e38f, qm = -3e38f;
        for (int s = 0; s < 4; s++) {
            pv[s] = apre  * scale * extra[s]     + H_pre_logits[s];
            qv[s] = apost * scale * extra[4 + s] + H_post_logits[s];
            pm = fmaxf(pm, pv[s]); qm = fmaxf(qm, qv[s]);
        }
        float ps = 0.f, qs = 0.f;
        for (int s = 0; s < 4; s++) {
            pv[s] = __expf(pv[s] - pm); qv[s] = __expf(qv[s] - qm);
            ps += pv[s]; qs += qv[s];
        }
        for (int s = 0; s < 4; s++) { hpre[s] = pv[s] / ps; hpost[s] = qv[s] / qs; }
    }

    // Sinkhorn, 10 iterations (u over rows, v over cols); Z[s][t] = Zl[s*16+t]
    const float lm = -2.772588722239781f;  // -log(16)
    for (int it = 0; it < 10; it++) {
        if (tid < 16) {
            int r = tid; float m = -3e38f;
            for (int c = 0; c < 16; c++) m = fmaxf(m, Zl[r * 16 + c] + vv[c]);
            float s2 = 0.f;
            for (int c = 0; c < 16; c++) s2 += __expf(Zl[r * 16 + c] + vv[c] - m);
            uu[r] = lm - (m + __logf(s2));
        }
        __syncthreads();
        if (tid < 16) {
            int c = tid; float m = -3e38f;
            for (int r = 0; r < 16; r++) m = fmaxf(m, Zl[r * 16 + c] + uu[r]);
            float s2 = 0.f;
            for (int r = 0; r < 16; r++) s2 += __expf(Zl[r * 16 + c] + uu[r] - m);
            vv[c] = lm - (m + __logf(s2));
        }
        __syncthreads();
    }
    // S = exp(Z+u+v)*16, in place
    Zl[tid] = __expf(Zl[tid] + uu[tid >> 4] + vv[tid & 15]) * 16.0f;
    __syncthreads();

    // mixed[tc][c] = sum_s S[s][tc] * bus[s*256+c]; add branch*H_post; write out
    float busr[16];
#pragma unroll
    for (int s = 0; s < 16; s++) busr[s] = busf[s * 256 + tid];
    const float* bo = branch_output + ((size_t)b * 2048 + l) * 1024;
#pragma unroll
    for (int tc = 0; tc < 16; tc++) {
        float acc2 = 0.f;
#pragma unroll
        for (int s = 0; s < 16; s++) acc2 += Zl[s * 16 + tc] * busr[s];
        int sout = tc >> 2, d = (tc & 3) * 256 + tid;
        float val = acc2 + bo[d] * hpost[sout];
        out[((size_t)(b * 4 + sout) * 2048 + l) * 1024 + d] = val;
    }

    // branch_input[d] = sum_s hpre[s] * bus[s*1024+d]
    int d0 = tid * 4;
    float4 bi; bi.x = bi.y = bi.z = bi.w = 0.f;
#pragma unroll
    for (int s = 0; s < 4; s++) {
        float4 v = *(const float4*)&busf[s * 1024 + d0];
        float h = hpre[s];
        bi.x += h * v.x; bi.y += h * v.y; bi.z += h * v.z; bi.w += h * v.w;
    }
    *(float4*)&out[OUT0 + ((size_t)b * 2048 + l) * 1024 + d0] = bi;
}

// ---------------------------------------------------------------------------
extern "C" void kernel_launch(void* const* d_in, const int* in_sizes, int n_in,
                              void* d_out, int out_size, void* d_ws, size_t ws_size,
                              hipStream_t stream) {
    const float* residuals  = (const float*)d_in[0];
    const float* branch_out = (const float*)d_in[1];
    const float* gamma      = (const float*)d_in[2];
    const float* H_res_log  = (const float*)d_in[3];
    const float* phi_res    = (const float*)d_in[4];
    const float* alpha_res  = (const float*)d_in[5];
    const float* H_pre_log  = (const float*)d_in[6];
    const float* phi_pre    = (const float*)d_in[7];
    const float* alpha_pre  = (const float*)d_in[8];
    const float* H_post_log = (const float*)d_in[9];
    const float* phi_post   = (const float*)d_in[10];
    const float* alpha_post = (const float*)d_in[11];

    unsigned short* W = (unsigned short*)d_ws;                       // 288*4096 bf16
    float* raw_part = (float*)((char*)d_ws + (size_t)NPAD * BUSW * 2); // 4*8192*288 f32
    float* out = (float*)d_out;

    hipLaunchKernelGGL(prep_w_kernel, dim3(NPAD * BUSW / 256), dim3(256), 0, stream,
                       gamma, phi_res, phi_pre, phi_post, W);
    hipLaunchKernelGGL(gemm_raw_kernel, dim3(NTOK / BM, KSPLIT), dim3(256), 0, stream,
                       residuals, W, raw_part);
    hipLaunchKernelGGL(fused_tail_kernel, dim3(NTOK), dim3(256), 0, stream,
                       residuals, branch_out, H_res_log, alpha_res,
                       H_pre_log, alpha_pre, H_post_log, alpha_post, raw_part, out);
}